// Round 5
// baseline (195.080 us; speedup 1.0000x reference)
//
#include <hip/hip_runtime.h>
#include <stdint.h>

#define BATCH 16
#define CIN   128
#define COUT  128
#define IMG_H 64
#define IMG_W 64
#define HW    4096
#define KTOT  1152          // 9*128
#define XH    66
#define XW    66
#define NCQ   16            // ci groups of 8
#define NSTEPS 18           // K-steps of 64 in wt4 layout
#define ASTEP 8192          // A elems per step-tile: 8cq*128co*8e (16 KB)
#define REPEAT 4            // measurement: GEMM dispatch = 4x work so it rises
                            // above the 43us fill floor into the top-5 counters.
                            // Idempotent (acc re-zeroed, out rewritten). Set to
                            // 1 next round once counters are captured.

typedef __attribute__((ext_vector_type(8))) __bf16 bf16x8;
typedef __attribute__((ext_vector_type(4))) float  f32x4;
typedef __attribute__((address_space(1))) const void* gas_p;
typedef __attribute__((address_space(3))) void*       las_p;

static __device__ __forceinline__ unsigned short f2bf(float f) {
  union { float f; uint32_t u; } c; c.f = f;
  uint32_t r = c.u + 0x7fffu + ((c.u >> 16) & 1u);   // RNE
  return (unsigned short)(r >> 16);
}

static __device__ __forceinline__ void gload_lds16(const unsigned short* g, unsigned short* l) {
  __builtin_amdgcn_global_load_lds((gas_p)g, (las_p)l, 16, 0, 0);
}

// ---- fused prep (unchanged, verified) ----
// blocks [0, 1024): x fp32 NCHW -> bf16 xpad[b][66][16cq][66][8], zero halo
// blocks [1024, 1312): w fp32 [b][co][ci][3][3] -> wt4[b][step18][cq8][co128][e8]
__global__ void prep_fused(const float* __restrict__ x, const float* __restrict__ w,
                           unsigned short* __restrict__ wt4, unsigned short* __restrict__ xpad) {
  const int t = threadIdx.x;
  if (blockIdx.x < BATCH * IMG_H) {
    __shared__ uint32_t tile[64 * 68];              // [wcol][ci2], pad 68 words
    const int b = blockIdx.x >> 6;
    const int h = blockIdx.x & 63;
    const float* xb = x + (size_t)b * CIN * HW + h * IMG_W;
    uint4* xp4 = (uint4*)xpad;                      // 16B chunks

    const int lane16 = t & 15;
    const int g      = t >> 4;
#pragma unroll
    for (int it = 0; it < 4; ++it) {
      const int ci = it * 32 + g * 2;
      const float4 va = *(const float4*)(xb + (size_t)ci * HW + lane16 * 4);
      const float4 vb = *(const float4*)(xb + (size_t)(ci + 1) * HW + lane16 * 4);
      const float av[4] = {va.x, va.y, va.z, va.w};
      const float bv[4] = {vb.x, vb.y, vb.z, vb.w};
#pragma unroll
      for (int cc = 0; cc < 4; ++cc)
        tile[(lane16 * 4 + cc) * 68 + it * 16 + g] =
            (uint32_t)f2bf(av[cc]) | ((uint32_t)f2bf(bv[cc]) << 16);
    }
    __syncthreads();

    const uint32_t rbase = ((uint32_t)b * XH + h + 1) * NCQ;
#pragma unroll
    for (int it = 0; it < 4; ++it) {
      const int o   = it * 256 + t;
      const int cqg = o >> 6;
      const int wc  = o & 63;
      const uint4 v = *(const uint4*)&tile[wc * 68 + cqg * 4];
      xp4[(rbase + cqg) * XW + wc + 1] = v;
    }
    if (t < 32) {
      const int cqg = t & 15;
      const int col = (t >> 4) ? 65 : 0;
      xp4[(rbase + cqg) * XW + col] = make_uint4(0, 0, 0, 0);
    }
    if (h == 0) {
      const uint32_t r0  = (uint32_t)b * XH * NCQ * XW;
      const uint32_t r65 = ((uint32_t)b * XH + 65) * NCQ * XW;
      for (int i = t; i < NCQ * XW; i += 256) {
        xp4[r0 + i]  = make_uint4(0, 0, 0, 0);
        xp4[r65 + i] = make_uint4(0, 0, 0, 0);
      }
    }
  } else {
    const int idx  = blockIdx.x - BATCH * IMG_H;
    const int b    = idx / NSTEPS;
    const int step = idx % NSTEPS;
    const int khkw = step >> 1;
    const int cib  = (step & 1) << 6;
    const float* wb = w + (size_t)b * COUT * KTOT;
    unsigned short* dst = wt4 + ((size_t)b * NSTEPS + step) * ASTEP;
#pragma unroll
    for (int i = 0; i < 4; ++i) {
      const int c  = i * 256 + t;                 // chunk 0..1023
      const int cq = c >> 7;
      const int co = c & 127;
      const int ci0 = cib + cq * 8;
      const float* src = wb + (size_t)co * KTOT + (size_t)ci0 * 9 + khkw;
      uint32_t p[4];
#pragma unroll
      for (int e = 0; e < 4; ++e)
        p[e] = (uint32_t)f2bf(src[(2 * e) * 9]) | ((uint32_t)f2bf(src[(2 * e + 1) * 9]) << 16);
      *(uint4*)&dst[(size_t)c * 8] = make_uint4(p[0], p[1], p[2], p[3]);
    }
  }
}

// ---- main implicit-GEMM: 128co x 128px per block, 4 waves of 64x64 tiles ----
// R2 skeleton (2 blocks/CU, dbuf, 1 barrier/step, 512 blocks, XCD-pinned
// batches) + R4 fragment economy (4x4 frags: 64 KB LDS reads/step vs 96 KB).
__global__ __launch_bounds__(256, 2) void dynconv_gemm(
    const unsigned short* __restrict__ wt4,   // [B][18][8][128][8] bf16
    const unsigned short* __restrict__ xpad,  // [B][66][16][66][8] bf16, halo=0
    float* __restrict__ out) {                // [B][COUT][64][64] fp32
  __shared__ alignas(16) unsigned short As[2][ASTEP];   // 2 x 16 KB
  __shared__ alignas(16) unsigned short Bs[2][ASTEP];   // 2 x 16 KB

  const int t   = threadIdx.x;
  const int bid = blockIdx.x;
  const int xcd = bid & 7;
  const int idx = bid >> 3;                 // 0..63 within XCD
  const int b   = xcd * 2 + (idx >> 5);     // batch (2 per XCD, slabs in L2)
  const int oh0 = (idx & 31) * 2;           // first of 2 output rows

  const int lane = t & 63;
  const int wave = t >> 6;                  // 0..3
  const int wm   = (wave & 1) << 6;         // co half of wave's compute tile
  const int wn   = (wave >> 1) << 6;        // px half of wave's compute tile
  const int l15  = lane & 15;
  const int quad = lane >> 4;

  // staging roles (independent of compute-tile roles):
  const int srow = wave & 1;                // px-row this wave stages
  const int scqo = wave >> 1;               // cq offset this wave stages

  // A source: thread's chunk = r*256 + t  (wt4 step layout [cq8][co128][e8])
  const unsigned short* abase = wt4 + (size_t)b * NSTEPS * ASTEP + (size_t)t * 8;
  const unsigned short* xb = xpad + (size_t)b * XH * NCQ * XW * 8;

  // STAGE(dst half u, step s): A 4 chunks/thread; B 4 chunks/thread.
  // B LDS chunk r*256 + wave*64 + lane == local (cq'=2r+scqo, px=srow*64+lane).
  // Global src: row oh0+srow+kh, cq cqb+scqo+2r, col kw+lane (per-lane!).
#define STAGE(U, S)                                                            \
  {                                                                            \
    const int khkw_ = (S) >> 1;                                                \
    const int kh_   = (khkw_ * 11) >> 5;                                       \
    const int kw_   = khkw_ - kh_ * 3;                                         \
    const int cqb_  = ((S) & 1) << 3;                                          \
    const unsigned short* astep_ = abase + (size_t)(S) * ASTEP;                \
    unsigned short* al_ = &As[U][wave * 512];                                  \
    unsigned short* bl_ = &Bs[U][wave * 512];                                  \
    const unsigned short* bsrc_ = xb +                                         \
        ((size_t)((oh0 + srow + kh_) * NCQ + cqb_ + scqo) * XW + kw_ + lane) * 8; \
    _Pragma("unroll")                                                          \
    for (int r_ = 0; r_ < 4; ++r_) {                                           \
      gload_lds16(astep_ + r_ * 2048, al_ + r_ * 2048);                        \
      gload_lds16(bsrc_ + (size_t)r_ * 2 * XW * 8, bl_ + r_ * 2048);           \
    }                                                                          \
  }

  for (int rep = 0; rep < REPEAT; ++rep) {
    f32x4 acc[4][4] = {};

    STAGE(0, 0);
    __syncthreads();

#pragma unroll 2
    for (int s = 0; s < NSTEPS; ++s) {
      const int u = s & 1;
      if (s + 1 < NSTEPS) STAGE(u ^ 1, s + 1);   // prefetch hides under MFMAs

      const unsigned short* ard = &As[u][0];
      const unsigned short* brd = &Bs[u][0];
#pragma unroll
      for (int ks = 0; ks < 2; ++ks) {
        const int cq = ks * 4 + quad;
        bf16x8 af[4], bf[4];
#pragma unroll
        for (int i = 0; i < 4; ++i)
          af[i] = *(const bf16x8*)&ard[(cq * 128 + wm + i * 16 + l15) * 8];
#pragma unroll
        for (int j = 0; j < 4; ++j)
          bf[j] = *(const bf16x8*)&brd[(cq * 128 + wn + j * 16 + l15) * 8];
#pragma unroll
        for (int i = 0; i < 4; ++i)
#pragma unroll
          for (int j = 0; j < 4; ++j)
            acc[i][j] = __builtin_amdgcn_mfma_f32_16x16x32_bf16(af[i], bf[j], acc[i][j], 0, 0, 0);
      }
      // one barrier/step: drains prefetch (vmcnt) + protects both halves
      __syncthreads();
    }

    // epilogue: wave's px half wn -> output row oh0 + (wn>>6), cols j*16+l15
    float* obase = out + (size_t)b * COUT * HW + (size_t)(oh0 + (wn >> 6)) * IMG_W;
#pragma unroll
    for (int i = 0; i < 4; ++i) {
#pragma unroll
      for (int r = 0; r < 4; ++r) {
        const int co = wm + i * 16 + quad * 4 + r;
        float* orow = obase + (size_t)co * HW;
#pragma unroll
        for (int j = 0; j < 4; ++j)
          orow[j * 16 + l15] = acc[i][j][r];
      }
    }
    // K-loop's final __syncthreads already ordered all LDS reads before this
    // point; next rep's STAGE(0,0) is therefore safe.
  }
#undef STAGE
}

// ---- safety net: direct fp32 conv ----
__global__ void dynconv_naive(const float* __restrict__ x, const float* __restrict__ w,
                              float* __restrict__ out) {
  const int o   = blockIdx.x * 256 + threadIdx.x;
  const int pix = o & (HW - 1);
  const int co  = (o >> 12) & (COUT - 1);
  const int b   = o >> 19;
  const int oh  = pix >> 6, ow = pix & 63;
  const float* xb = x + (size_t)b * CIN * HW;
  const float* wb = w + ((size_t)b * COUT + co) * CIN * 9;
  float s = 0.f;
  for (int ci = 0; ci < CIN; ++ci) {
    const float* xc = xb + ci * HW;
    const float* wc = wb + ci * 9;
#pragma unroll
    for (int kh = 0; kh < 3; ++kh) {
      const int ih = oh + kh - 1;
      if ((unsigned)ih >= IMG_H) continue;
#pragma unroll
      for (int kw = 0; kw < 3; ++kw) {
        const int iw = ow + kw - 1;
        if ((unsigned)iw >= IMG_W) continue;
        s += xc[ih * IMG_W + iw] * wc[kh * 3 + kw];
      }
    }
  }
  out[o] = s;
}

extern "C" void kernel_launch(void* const* d_in, const int* in_sizes, int n_in,
                              void* d_out, int out_size, void* d_ws, size_t ws_size,
                              hipStream_t stream) {
  const float* x = (const float*)d_in[0];
  const float* w = (const float*)d_in[1];
  float* out = (float*)d_out;

  const size_t wt_bytes = (size_t)BATCH * NSTEPS * ASTEP * sizeof(unsigned short);       //  4.72 MB
  const size_t xp_bytes = (size_t)BATCH * XH * NCQ * XW * 8 * sizeof(unsigned short);    // 17.84 MB

  if (ws_size >= wt_bytes + xp_bytes) {
    unsigned short* wt4  = (unsigned short*)d_ws;
    unsigned short* xpad = (unsigned short*)((char*)d_ws + wt_bytes);
    prep_fused<<<BATCH * IMG_H + BATCH * NSTEPS, 256, 0, stream>>>(x, w, wt4, xpad);
    dynconv_gemm<<<512, 256, 0, stream>>>(wt4, xpad, out);
  } else {
    dynconv_naive<<<(BATCH * COUT * HW) / 256, 256, 0, stream>>>(x, w, out);
  }
}

// Round 7
// 125.462 us; speedup vs baseline: 1.5549x; 1.5549x over previous
//
#include <hip/hip_runtime.h>
#include <stdint.h>

#define BATCH 16
#define CIN   128
#define COUT  128
#define IMG_H 64
#define IMG_W 64
#define HW    4096
#define KTOT  1152          // 9*128
#define XH    66
#define XW    66
#define NCQ   16            // ci groups of 8
#define NSTEPS 18           // K-steps of 64 in wt4 layout
#define ASTEP 8192          // A elems per step-tile: 8cq*128co*8e (16 KB)
#define AHALF 4096          // A elems per half-step: 4cq*128co*8e (8 KB)
#define BHALF 4096          // B elems per half-step: 4cq*128px*8e (8 KB)
#define NH    36            // half-steps of K=32

typedef __attribute__((ext_vector_type(8))) __bf16 bf16x8;
typedef __attribute__((ext_vector_type(4))) float  f32x4;
typedef __attribute__((address_space(1))) const void* gas_p;
typedef __attribute__((address_space(3))) void*       las_p;

static __device__ __forceinline__ unsigned short f2bf(float f) {
  union { float f; uint32_t u; } c; c.f = f;
  uint32_t r = c.u + 0x7fffu + ((c.u >> 16) & 1u);   // RNE
  return (unsigned short)(r >> 16);
}

static __device__ __forceinline__ void gload_lds16(const unsigned short* g, unsigned short* l) {
  __builtin_amdgcn_global_load_lds((gas_p)g, (las_p)l, 16, 0, 0);
}

// ---- fused prep (unchanged, verified) ----
__global__ void prep_fused(const float* __restrict__ x, const float* __restrict__ w,
                           unsigned short* __restrict__ wt4, unsigned short* __restrict__ xpad) {
  const int t = threadIdx.x;
  if (blockIdx.x < BATCH * IMG_H) {
    __shared__ uint32_t tile[64 * 68];              // [wcol][ci2], pad 68 words
    const int b = blockIdx.x >> 6;
    const int h = blockIdx.x & 63;
    const float* xb = x + (size_t)b * CIN * HW + h * IMG_W;
    uint4* xp4 = (uint4*)xpad;                      // 16B chunks

    const int lane16 = t & 15;
    const int g      = t >> 4;
#pragma unroll
    for (int it = 0; it < 4; ++it) {
      const int ci = it * 32 + g * 2;
      const float4 va = *(const float4*)(xb + (size_t)ci * HW + lane16 * 4);
      const float4 vb = *(const float4*)(xb + (size_t)(ci + 1) * HW + lane16 * 4);
      const float av[4] = {va.x, va.y, va.z, va.w};
      const float bv[4] = {vb.x, vb.y, vb.z, vb.w};
#pragma unroll
      for (int cc = 0; cc < 4; ++cc)
        tile[(lane16 * 4 + cc) * 68 + it * 16 + g] =
            (uint32_t)f2bf(av[cc]) | ((uint32_t)f2bf(bv[cc]) << 16);
    }
    __syncthreads();

    const uint32_t rbase = ((uint32_t)b * XH + h + 1) * NCQ;
#pragma unroll
    for (int it = 0; it < 4; ++it) {
      const int o   = it * 256 + t;
      const int cqg = o >> 6;
      const int wc  = o & 63;
      const uint4 v = *(const uint4*)&tile[wc * 68 + cqg * 4];
      xp4[(rbase + cqg) * XW + wc + 1] = v;
    }
    if (t < 32) {
      const int cqg = t & 15;
      const int col = (t >> 4) ? 65 : 0;
      xp4[(rbase + cqg) * XW + col] = make_uint4(0, 0, 0, 0);
    }
    if (h == 0) {
      const uint32_t r0  = (uint32_t)b * XH * NCQ * XW;
      const uint32_t r65 = ((uint32_t)b * XH + 65) * NCQ * XW;
      for (int i = t; i < NCQ * XW; i += 256) {
        xp4[r0 + i]  = make_uint4(0, 0, 0, 0);
        xp4[r65 + i] = make_uint4(0, 0, 0, 0);
      }
    }
  } else {
    const int idx  = blockIdx.x - BATCH * IMG_H;
    const int b    = idx / NSTEPS;
    const int step = idx % NSTEPS;
    const int khkw = step >> 1;
    const int cib  = (step & 1) << 6;
    const float* wb = w + (size_t)b * COUT * KTOT;
    unsigned short* dst = wt4 + ((size_t)b * NSTEPS + step) * ASTEP;
#pragma unroll
    for (int i = 0; i < 4; ++i) {
      const int c  = i * 256 + t;                 // chunk 0..1023
      const int cq = c >> 7;
      const int co = c & 127;
      const int ci0 = cib + cq * 8;
      const float* src = wb + (size_t)co * KTOT + (size_t)ci0 * 9 + khkw;
      uint32_t p[4];
#pragma unroll
      for (int e = 0; e < 4; ++e)
        p[e] = (uint32_t)f2bf(src[(2 * e) * 9]) | ((uint32_t)f2bf(src[(2 * e + 1) * 9]) << 16);
      *(uint4*)&dst[(size_t)c * 8] = make_uint4(p[0], p[1], p[2], p[3]);
    }
  }
}

// ---- main implicit-GEMM: 128co x 128px per block, 4 waves of 64x64 ----
// T4 counted-vmcnt pipeline: K in 36 half-steps of 32ci; 3 LDS buffer sets
// (A 8KB + B 8KB each, 48 KB total -> 2 blocks/CU); prefetch depth 2.
// Per half-step: issue loads(h+2); compute(h); s_waitcnt vmcnt(4) (drains own
// loads(h+1), keeps loads(h+2) in flight); raw s_barrier. Every wave drains
// its OWN h+1 loads before the barrier => after the barrier all waves' h+1
// data is resident. Never vmcnt(0) in steady state (m218: drain-0 costs 38%+).
__global__ __launch_bounds__(256, 2) void dynconv_gemm(
    const unsigned short* __restrict__ wt4,   // [B][18][8][128][8] bf16
    const unsigned short* __restrict__ xpad,  // [B][66][16][66][8] bf16, halo=0
    float* __restrict__ out) {                // [B][COUT][64][64] fp32
  __shared__ alignas(16) unsigned short As[3][AHALF];   // 3 x 8 KB
  __shared__ alignas(16) unsigned short Bs[3][BHALF];   // 3 x 8 KB

  const int t   = threadIdx.x;
  const int bid = blockIdx.x;
  const int xcd = bid & 7;
  const int idx = bid >> 3;                 // 0..63 within XCD
  const int b   = xcd * 2 + (idx >> 5);     // batch (2 per XCD, slabs in L2)
  const int oh0 = (idx & 31) * 2;           // first of 2 output rows

  const int lane = t & 63;
  const int wave = t >> 6;                  // 0..3
  const int wm   = (wave & 1) << 6;         // co half of wave's compute tile
  const int wn   = (wave >> 1) << 6;        // px half of wave's compute tile
  const int l15  = lane & 15;
  const int quad = lane >> 4;

  // staging roles: wave stages B rows srow, cq pair {scq, scq+2}
  const int srow = wave & 1;
  const int scq  = wave >> 1;

  const unsigned short* wt4b = wt4 + (size_t)b * NSTEPS * ASTEP;
  const unsigned short* xb   = xpad + (size_t)b * XH * NCQ * XW * 8;

  // STAGE half-step H into buffer set BUF.
  // A half [cq'4][co128][e8]: thread chunk c = r*256+t, r in {0,1};
  //   global elem = (H>>1)*ASTEP + (H&1)*AHALF + c*8 (per-lane source!).
  // B half [cq'4][px128][e8]: chunk cb = r*256 + wave*64 + lane
  //   -> cq' = r*2 + (wave>>1), px = (wave&1)*64 + lane.
  //   global: row oh0+srow+kh, cq cqb+cq', col kw+lane.
#define STAGE(BUF, H)                                                          \
  {                                                                            \
    const int h_    = (H);                                                     \
    const int khkw_ = h_ >> 2;                                                 \
    const int kh_   = (khkw_ * 11) >> 5;                                       \
    const int kw_   = khkw_ - kh_ * 3;                                         \
    const int cqb_  = (((h_ >> 1) & 1) << 3) + ((h_ & 1) << 2);                \
    const unsigned short* ah_ = wt4b + (size_t)(h_ >> 1) * ASTEP +             \
                                (size_t)(h_ & 1) * AHALF + (size_t)t * 8;      \
    unsigned short* al_ = &As[BUF][wave * 512];                                \
    unsigned short* bl_ = &Bs[BUF][wave * 512];                                \
    const unsigned short* bs_ = xb +                                           \
        ((size_t)((oh0 + srow + kh_) * NCQ + cqb_ + scq) * XW + kw_ + lane) * 8; \
    gload_lds16(ah_,        al_);                                              \
    gload_lds16(ah_ + 2048, al_ + 2048);                                       \
    gload_lds16(bs_,                      bl_);                                \
    gload_lds16(bs_ + (size_t)2 * XW * 8, bl_ + 2048);                         \
  }

#define COMPUTE(BUF)                                                           \
  {                                                                            \
    const unsigned short* a_ = &As[BUF][0];                                    \
    const unsigned short* b_ = &Bs[BUF][0];                                    \
    bf16x8 af[4], bf[4];                                                       \
    _Pragma("unroll")                                                          \
    for (int i = 0; i < 4; ++i)                                                \
      af[i] = *(const bf16x8*)&a_[(quad * 128 + wm + i * 16 + l15) * 8];       \
    _Pragma("unroll")                                                          \
    for (int j = 0; j < 4; ++j)                                                \
      bf[j] = *(const bf16x8*)&b_[(quad * 128 + wn + j * 16 + l15) * 8];       \
    _Pragma("unroll")                                                          \
    for (int i = 0; i < 4; ++i)                                                \
      _Pragma("unroll")                                                        \
      for (int j = 0; j < 4; ++j)                                              \
        acc[i][j] = __builtin_amdgcn_mfma_f32_16x16x32_bf16(af[i], bf[j],      \
                                                            acc[i][j], 0, 0, 0); \
  }

#define SYNC_VM4                                                               \
  asm volatile("s_waitcnt vmcnt(4)" ::: "memory");                             \
  __builtin_amdgcn_sched_barrier(0);                                           \
  __builtin_amdgcn_s_barrier();                                                \
  __builtin_amdgcn_sched_barrier(0);

#define SYNC_VM0                                                               \
  asm volatile("s_waitcnt vmcnt(0)" ::: "memory");                             \
  __builtin_amdgcn_sched_barrier(0);                                           \
  __builtin_amdgcn_s_barrier();                                                \
  __builtin_amdgcn_sched_barrier(0);

  f32x4 acc[4][4] = {};

  // prologue: h0 -> buf0, h1 -> buf1 (8 loads); drain h0 only, keep h1 flying
  STAGE(0, 0);
  STAGE(1, 1);
  SYNC_VM4;

  // steady state: h = 0..32 in groups of 3 (buffer = h%3)
  for (int hb = 0; hb < 11; ++hb) {
    const int h = hb * 3;
    STAGE(2, h + 2); COMPUTE(0); SYNC_VM4;
    STAGE(0, h + 3); COMPUTE(1); SYNC_VM4;
    STAGE(1, h + 4); COMPUTE(2); SYNC_VM4;
  }
  // tail: h=33 (stage 35), h=34 (nothing left; drain all), h=35
  STAGE(2, 35); COMPUTE(0); SYNC_VM4;   // drains h34, h35 in flight
  COMPUTE(1); SYNC_VM0;                 // drains h35
  COMPUTE(2);

#undef STAGE
#undef COMPUTE
#undef SYNC_VM4
#undef SYNC_VM0

  // epilogue (verified R5): co = wm + i*16 + quad*4 + r;
  // out row = oh0 + (wn>>6), cols j*16 + l15
  float* obase = out + (size_t)b * COUT * HW + (size_t)(oh0 + (wn >> 6)) * IMG_W;
#pragma unroll
  for (int i = 0; i < 4; ++i) {
#pragma unroll
    for (int r = 0; r < 4; ++r) {
      const int co = wm + i * 16 + quad * 4 + r;
      float* orow = obase + (size_t)co * HW;
#pragma unroll
      for (int j = 0; j < 4; ++j)
        orow[j * 16 + l15] = acc[i][j][r];
    }
  }
}

// ---- safety net: direct fp32 conv ----
__global__ void dynconv_naive(const float* __restrict__ x, const float* __restrict__ w,
                              float* __restrict__ out) {
  const int o   = blockIdx.x * 256 + threadIdx.x;
  const int pix = o & (HW - 1);
  const int co  = (o >> 12) & (COUT - 1);
  const int b   = o >> 19;
  const int oh  = pix >> 6, ow = pix & 63;
  const float* xb = x + (size_t)b * CIN * HW;
  const float* wb = w + ((size_t)b * COUT + co) * CIN * 9;
  float s = 0.f;
  for (int ci = 0; ci < CIN; ++ci) {
    const float* xc = xb + ci * HW;
    const float* wc = wb + ci * 9;
#pragma unroll
    for (int kh = 0; kh < 3; ++kh) {
      const int ih = oh + kh - 1;
      if ((unsigned)ih >= IMG_H) continue;
#pragma unroll
      for (int kw = 0; kw < 3; ++kw) {
        const int iw = ow + kw - 1;
        if ((unsigned)iw >= IMG_W) continue;
        s += xc[ih * IMG_W + iw] * wc[kh * 3 + kw];
      }
    }
  }
  out[o] = s;
}

extern "C" void kernel_launch(void* const* d_in, const int* in_sizes, int n_in,
                              void* d_out, int out_size, void* d_ws, size_t ws_size,
                              hipStream_t stream) {
  const float* x = (const float*)d_in[0];
  const float* w = (const float*)d_in[1];
  float* out = (float*)d_out;

  const size_t wt_bytes = (size_t)BATCH * NSTEPS * ASTEP * sizeof(unsigned short);       //  4.72 MB
  const size_t xp_bytes = (size_t)BATCH * XH * NCQ * XW * 8 * sizeof(unsigned short);    // 17.84 MB

  if (ws_size >= wt_bytes + xp_bytes) {
    unsigned short* wt4  = (unsigned short*)d_ws;
    unsigned short* xpad = (unsigned short*)((char*)d_ws + wt_bytes);
    prep_fused<<<BATCH * IMG_H + BATCH * NSTEPS, 256, 0, stream>>>(x, w, wt4, xpad);
    dynconv_gemm<<<512, 256, 0, stream>>>(wt4, xpad, out);
  } else {
    dynconv_naive<<<(BATCH * COUT * HW) / 256, 256, 0, stream>>>(x, w, out);
  }
}

// Round 8
// 119.638 us; speedup vs baseline: 1.6306x; 1.0487x over previous
//
#include <hip/hip_runtime.h>
#include <stdint.h>

#define BATCH 16
#define CIN   128
#define COUT  128
#define IMG_H 64
#define IMG_W 64
#define HW    4096
#define KTOT  1152          // 9*128
#define XH    66
#define XW    66
#define NCQ   16            // ci groups of 8
#define NSTEPS 18           // K-steps of 64 in wt4 layout
#define ASTEP 8192          // A elems per step-tile: 8cq*128co*8e (16 KB)

typedef __attribute__((ext_vector_type(8))) __bf16 bf16x8;
typedef __attribute__((ext_vector_type(4))) float  f32x4;
typedef __attribute__((address_space(1))) const void* gas_p;
typedef __attribute__((address_space(3))) void*       las_p;

static __device__ __forceinline__ unsigned short f2bf(float f) {
  union { float f; uint32_t u; } c; c.f = f;
  uint32_t r = c.u + 0x7fffu + ((c.u >> 16) & 1u);   // RNE
  return (unsigned short)(r >> 16);
}

static __device__ __forceinline__ void gload_lds16(const unsigned short* g, unsigned short* l) {
  __builtin_amdgcn_global_load_lds((gas_p)g, (las_p)l, 16, 0, 0);
}

// ---- fused prep (unchanged, verified) ----
__global__ void prep_fused(const float* __restrict__ x, const float* __restrict__ w,
                           unsigned short* __restrict__ wt4, unsigned short* __restrict__ xpad) {
  const int t = threadIdx.x;
  if (blockIdx.x < BATCH * IMG_H) {
    __shared__ uint32_t tile[64 * 68];              // [wcol][ci2], pad 68 words
    const int b = blockIdx.x >> 6;
    const int h = blockIdx.x & 63;
    const float* xb = x + (size_t)b * CIN * HW + h * IMG_W;
    uint4* xp4 = (uint4*)xpad;                      // 16B chunks

    const int lane16 = t & 15;
    const int g      = t >> 4;
#pragma unroll
    for (int it = 0; it < 4; ++it) {
      const int ci = it * 32 + g * 2;
      const float4 va = *(const float4*)(xb + (size_t)ci * HW + lane16 * 4);
      const float4 vb = *(const float4*)(xb + (size_t)(ci + 1) * HW + lane16 * 4);
      const float av[4] = {va.x, va.y, va.z, va.w};
      const float bv[4] = {vb.x, vb.y, vb.z, vb.w};
#pragma unroll
      for (int cc = 0; cc < 4; ++cc)
        tile[(lane16 * 4 + cc) * 68 + it * 16 + g] =
            (uint32_t)f2bf(av[cc]) | ((uint32_t)f2bf(bv[cc]) << 16);
    }
    __syncthreads();

    const uint32_t rbase = ((uint32_t)b * XH + h + 1) * NCQ;
#pragma unroll
    for (int it = 0; it < 4; ++it) {
      const int o   = it * 256 + t;
      const int cqg = o >> 6;
      const int wc  = o & 63;
      const uint4 v = *(const uint4*)&tile[wc * 68 + cqg * 4];
      xp4[(rbase + cqg) * XW + wc + 1] = v;
    }
    if (t < 32) {
      const int cqg = t & 15;
      const int col = (t >> 4) ? 65 : 0;
      xp4[(rbase + cqg) * XW + col] = make_uint4(0, 0, 0, 0);
    }
    if (h == 0) {
      const uint32_t r0  = (uint32_t)b * XH * NCQ * XW;
      const uint32_t r65 = ((uint32_t)b * XH + 65) * NCQ * XW;
      for (int i = t; i < NCQ * XW; i += 256) {
        xp4[r0 + i]  = make_uint4(0, 0, 0, 0);
        xp4[r65 + i] = make_uint4(0, 0, 0, 0);
      }
    }
  } else {
    const int idx  = blockIdx.x - BATCH * IMG_H;
    const int b    = idx / NSTEPS;
    const int step = idx % NSTEPS;
    const int khkw = step >> 1;
    const int cib  = (step & 1) << 6;
    const float* wb = w + (size_t)b * COUT * KTOT;
    unsigned short* dst = wt4 + ((size_t)b * NSTEPS + step) * ASTEP;
#pragma unroll
    for (int i = 0; i < 4; ++i) {
      const int c  = i * 256 + t;                 // chunk 0..1023
      const int cq = c >> 7;
      const int co = c & 127;
      const int ci0 = cib + cq * 8;
      const float* src = wb + (size_t)co * KTOT + (size_t)ci0 * 9 + khkw;
      uint32_t p[4];
#pragma unroll
      for (int e = 0; e < 4; ++e)
        p[e] = (uint32_t)f2bf(src[(2 * e) * 9]) | ((uint32_t)f2bf(src[(2 * e + 1) * 9]) << 16);
      *(uint4*)&dst[(size_t)c * 8] = make_uint4(p[0], p[1], p[2], p[3]);
    }
  }
}

// ---- main implicit-GEMM: 128co x 128px per block, 8 waves, K-SPLIT ----
// 8 waves = 4 output tiles (64co x 64px) x 2 K-halves (cq 0-3 / 4-7).
// 16 waves/CU (2 blocks x 8 waves, 4/SIMD) to hide LDS+L2 latency; LDS
// traffic per step unchanged vs R5 (64 KB/block). Double-buffered LDS
// (64 KB), proven __syncthreads protocol. Final cross-wave K-reduction
// through the (dead) LDS buffers with lane-rotated slots (bank-safe).
__global__ __launch_bounds__(512, 4) void dynconv_gemm(
    const unsigned short* __restrict__ wt4,   // [B][18][8][128][8] bf16
    const unsigned short* __restrict__ xpad,  // [B][66][16][66][8] bf16, halo=0
    float* __restrict__ out) {                // [B][COUT][64][64] fp32
  __shared__ alignas(16) unsigned short SH[4][ASTEP];   // 64 KB total
  // SH[0..1] = A dbuf, SH[2..3] = B dbuf; reused as 64 KB f32 reduce buffer.

  const int t   = threadIdx.x;
  const int bid = blockIdx.x;
  const int xcd = bid & 7;
  const int idx = bid >> 3;                 // 0..63 within XCD
  const int b   = xcd * 2 + (idx >> 5);     // batch (2 per XCD, slabs in L2)
  const int oh0 = (idx & 31) * 2;           // first of 2 output rows

  const int lane = t & 63;
  const int wave = t >> 6;                  // 0..7
  const int wm   = (wave & 1) << 6;         // co half of wave's tile
  const int wn   = ((wave >> 1) & 1) << 6;  // px half of wave's tile
  const int kg   = wave >> 2;               // K-group: cq 0-3 or 4-7
  const int l15  = lane & 15;
  const int quad = lane >> 4;

  const unsigned short* wt4b = wt4 + (size_t)b * NSTEPS * ASTEP;
  const unsigned short* xb   = xpad + (size_t)b * XH * NCQ * XW * 8;

  // STAGE step S into dbuf half U. 2048 chunks total, 4 per thread.
  // A chunk c = r*512+t: (cq,co) = (c>>7, c&127); linear in wt4 step tile.
  // B chunk c = r*512 + wave*64 + lane: cq' = r*4 + (wave>>1),
  //   px = (wave&1)*64 + lane. Global: row oh0+(wave&1)+kh, cq cqb+cq',
  //   col kw+lane (per-lane source; wave-uniform LDS dst).
#define STAGE(U, S)                                                           \
  {                                                                           \
    const int khkw_ = (S) >> 1;                                               \
    const int kh_   = (khkw_ * 11) >> 5;                                      \
    const int kw_   = khkw_ - kh_ * 3;                                        \
    const int cqb_  = ((S) & 1) << 3;                                         \
    const unsigned short* astep_ = wt4b + (size_t)(S) * ASTEP;                \
    _Pragma("unroll")                                                         \
    for (int r_ = 0; r_ < 2; ++r_) {                                          \
      gload_lds16(astep_ + (size_t)(r_ * 512 + t) * 8,                        \
                  &SH[U][(r_ * 512 + wave * 64) * 8]);                        \
      const unsigned short* bs_ = xb +                                        \
          ((size_t)((oh0 + (wave & 1) + kh_) * NCQ + cqb_ + r_ * 4 +          \
                    (wave >> 1)) * XW + kw_ + lane) * 8;                      \
      gload_lds16(bs_, &SH[2 + (U)][(r_ * 512 + wave * 64) * 8]);             \
    }                                                                         \
  }

  f32x4 acc[4][4] = {};

  STAGE(0, 0);
  __syncthreads();

#pragma unroll 2
  for (int s = 0; s < NSTEPS; ++s) {
    const int u = s & 1;
    if (s + 1 < NSTEPS) STAGE(u ^ 1, s + 1);   // prefetch next step

    // this wave's K-half: cq = kg*4 + quad (one K=32 slice per step)
    const int cq = kg * 4 + quad;
    const unsigned short* a_ = &SH[u][0];
    const unsigned short* b_ = &SH[2 + u][0];
    bf16x8 af[4], bf[4];
#pragma unroll
    for (int i = 0; i < 4; ++i)
      af[i] = *(const bf16x8*)&a_[(cq * 128 + wm + i * 16 + l15) * 8];
#pragma unroll
    for (int j = 0; j < 4; ++j)
      bf[j] = *(const bf16x8*)&b_[(cq * 128 + wn + j * 16 + l15) * 8];
#pragma unroll
    for (int i = 0; i < 4; ++i)
#pragma unroll
      for (int j = 0; j < 4; ++j)
        acc[i][j] = __builtin_amdgcn_mfma_f32_16x16x32_bf16(af[i], bf[j], acc[i][j], 0, 0, 0);

    __syncthreads();   // drains prefetch + protects both dbuf halves
  }
#undef STAGE

  // ---- cross-wave K-reduction through LDS (buffers now dead) ----
  // Thread row = 256B => naive layout is a 32-way bank conflict; rotate the
  // 16B chunk slot by lane: data chunk m lives at slot (m+lane)&15. Writer
  // (wave w+4) and reader (wave w) use the same lane => same slots. Static
  // chunk index m keeps acc[] register-resident (rule #20).
  float* red = (float*)&SH[0][0];   // 64 KB = 4 waves x 64 lanes x 64 f32
  if (wave >= 4) {
    float* row = red + (size_t)((wave - 4) * 64 + lane) * 64;
#pragma unroll
    for (int m = 0; m < 16; ++m)
      *(f32x4*)&row[((m + lane) & 15) * 4] = acc[m >> 2][m & 3];
  }
  __syncthreads();
  if (wave < 4) {
    const float* row = red + (size_t)(wave * 64 + lane) * 64;
#pragma unroll
    for (int m = 0; m < 16; ++m) {
      const f32x4 v = *(const f32x4*)&row[((m + lane) & 15) * 4];
      acc[m >> 2][m & 3] += v;
    }

    // epilogue (verified R5 algebra): co = wm + i*16 + quad*4 + r;
    // out row = oh0 + (wn>>6), cols j*16 + l15
    float* obase = out + (size_t)b * COUT * HW + (size_t)(oh0 + (wn >> 6)) * IMG_W;
#pragma unroll
    for (int i = 0; i < 4; ++i) {
#pragma unroll
      for (int r = 0; r < 4; ++r) {
        const int co = wm + i * 16 + quad * 4 + r;
        float* orow = obase + (size_t)co * HW;
#pragma unroll
        for (int j = 0; j < 4; ++j)
          orow[j * 16 + l15] = acc[i][j][r];
      }
    }
  }
}

// ---- safety net: direct fp32 conv ----
__global__ void dynconv_naive(const float* __restrict__ x, const float* __restrict__ w,
                              float* __restrict__ out) {
  const int o   = blockIdx.x * 256 + threadIdx.x;
  const int pix = o & (HW - 1);
  const int co  = (o >> 12) & (COUT - 1);
  const int b   = o >> 19;
  const int oh  = pix >> 6, ow = pix & 63;
  const float* xb = x + (size_t)b * CIN * HW;
  const float* wb = w + ((size_t)b * COUT + co) * CIN * 9;
  float s = 0.f;
  for (int ci = 0; ci < CIN; ++ci) {
    const float* xc = xb + ci * HW;
    const float* wc = wb + ci * 9;
#pragma unroll
    for (int kh = 0; kh < 3; ++kh) {
      const int ih = oh + kh - 1;
      if ((unsigned)ih >= IMG_H) continue;
#pragma unroll
      for (int kw = 0; kw < 3; ++kw) {
        const int iw = ow + kw - 1;
        if ((unsigned)iw >= IMG_W) continue;
        s += xc[ih * IMG_W + iw] * wc[kh * 3 + kw];
      }
    }
  }
  out[o] = s;
}

extern "C" void kernel_launch(void* const* d_in, const int* in_sizes, int n_in,
                              void* d_out, int out_size, void* d_ws, size_t ws_size,
                              hipStream_t stream) {
  const float* x = (const float*)d_in[0];
  const float* w = (const float*)d_in[1];
  float* out = (float*)d_out;

  const size_t wt_bytes = (size_t)BATCH * NSTEPS * ASTEP * sizeof(unsigned short);       //  4.72 MB
  const size_t xp_bytes = (size_t)BATCH * XH * NCQ * XW * 8 * sizeof(unsigned short);    // 17.84 MB

  if (ws_size >= wt_bytes + xp_bytes) {
    unsigned short* wt4  = (unsigned short*)d_ws;
    unsigned short* xpad = (unsigned short*)((char*)d_ws + wt_bytes);
    prep_fused<<<BATCH * IMG_H + BATCH * NSTEPS, 256, 0, stream>>>(x, w, wt4, xpad);
    dynconv_gemm<<<512, 512, 0, stream>>>(wt4, xpad, out);
  } else {
    dynconv_naive<<<(BATCH * COUT * HW) / 256, 256, 0, stream>>>(x, w, out);
  }
}